// Round 3
// baseline (103.746 us; speedup 1.0000x reference)
//
#include <hip/hip_runtime.h>

#define SENT    256
#define BATCH   64
#define WLEN    16
#define D_WORDE 300
#define D_CHARE 50
#define OUT_CH  200
#define KSIZE   3
#define NPOS    14
#define D_OUT   500
#define NWORDS  (SENT * BATCH)

// GEMM geometry: M=16 positions/word, N=13x16=208 out-ch, K=3*64=192 (kg=kk*64+c)
#define KPAD      192
#define MPAD      208
#define CHARP_U16 (129 * 64)          // row 128 = zeros (conv rows 16/17)
#define WO_U16    (MPAD * KPAD)
#define WS_NEED   ((size_t)(CHARP_U16 + WO_U16) * 2)

// wave decomposition: classes 0..3 own tiles {3c,3c+1,3c+2} x 8-word chunks (2048 each)
// class 4 owns tile 12 x 32-word chunks (512)
#define CLASS_WAVES   2048
#define T12_WAVES     512
#define CONV_WAVES    (4 * CLASS_WAVES + T12_WAVES)   // 8704
#define CONV_BLOCKS   (CONV_WAVES / 4)                // 2176
#define EMB_BLOCKS    (NWORDS / 4)                    // 4096

typedef short  short8  __attribute__((ext_vector_type(8)));
typedef float  float4v __attribute__((ext_vector_type(4)));

__device__ __forceinline__ ushort f2bf(float f) {
    unsigned u = __float_as_uint(f);
    u = (u + 0x7FFFu + ((u >> 16) & 1u)) >> 16;   // RNE
    return (ushort)u;
}

// ---------- prep: bf16 char table (129 rows, padded) + K-major conv weights ----------
__global__ void prep_kernel(const float* __restrict__ W_char,
                            const float* __restrict__ conv_w,
                            ushort* __restrict__ ws) {
    int j = blockIdx.x * 256 + threadIdx.x;
    if (j < CHARP_U16) {
        int r = j >> 6, c = j & 63;
        ws[j] = (r < 128 && c < D_CHARE) ? f2bf(W_char[r * D_CHARE + c]) : (ushort)0;
    }
    int j2 = j - CHARP_U16;
    if (j2 >= 0 && j2 < WO_U16) {
        int o = j2 / KPAD, kg = j2 - o * KPAD;
        int kk = kg >> 6, c = kg & 63;
        float v = (o < OUT_CH && c < D_CHARE)
                    ? conv_w[o * (D_CHARE * KSIZE) + c * KSIZE + kk] : 0.f;
        ws[CHARP_U16 + j2] = f2bf(v);
    }
}

__device__ __forceinline__ float redmax14(float4v d, int lg) {
    float m01 = fmaxf(d[0], d[1]);
    float m23 = fmaxf(d[2], d[3]);
    float m = (lg == 3) ? m01 : fmaxf(m01, m23);   // rows 14,15 invalid
    m = fmaxf(m, __shfl_xor(m, 16, 64));
    m = fmaxf(m, __shfl_xor(m, 32, 64));
    return m;
}

// NT tiles starting at tile tbase; words [w0, w0+WCNT)
template <int NT, int WCNT>
__device__ __forceinline__ void conv_wave(int tbase, int w0, int lane,
                                          const int* __restrict__ chars,
                                          const ushort* __restrict__ charP,
                                          const ushort* __restrict__ WO,
                                          const float* __restrict__ conv_b,
                                          float* __restrict__ out) {
    const int l15 = lane & 15;
    const int lg  = lane >> 4;

    short8 B[NT][6];
    float  bv[NT];
    #pragma unroll
    for (int i = 0; i < NT; i++) {
        int t = tbase + i;
        int col = t * 16 + l15;
        #pragma unroll
        for (int s = 0; s < 6; s++)
            B[i][s] = *(const short8*)&WO[col * KPAD + s * 32 + lg * 8];
        bv[i] = (col < OUT_CH) ? conv_b[col] : 0.f;
    }

    #pragma unroll 1
    for (int r = 0; r < WCNT; r++) {
        const int m = w0 + r;
        // 16 char ids for this word; lanes >=16 hold the zero-row id (128)
        int iv = 128;
        if (lane < WLEN)
            iv = chars[((m & 63) * SENT + (m >> 6)) * WLEN + lane];
        const int id0 = __shfl(iv, l15,     64);
        const int id1 = __shfl(iv, l15 + 1, 64);
        const int id2 = __shfl(iv, l15 + 2, 64);

        short8 a[6];
        #pragma unroll
        for (int s = 0; s < 6; s++) {
            int id = (s < 2) ? id0 : (s < 4) ? id1 : id2;
            a[s] = *(const short8*)&charP[id * 64 + (s & 1) * 32 + lg * 8];
        }

        float4v acc[NT];
        #pragma unroll
        for (int i = 0; i < NT; i++) acc[i] = (float4v){0, 0, 0, 0};
        #pragma unroll
        for (int s = 0; s < 6; s++)
            #pragma unroll
            for (int i = 0; i < NT; i++)
                acc[i] = __builtin_amdgcn_mfma_f32_16x16x32_bf16(a[s], B[i][s], acc[i], 0, 0, 0);

        float* obase = out + (size_t)m * D_OUT + D_WORDE;
        #pragma unroll
        for (int i = 0; i < NT; i++) {
            float mx = redmax14(acc[i], lg) + bv[i];
            int col = (tbase + i) * 16 + lane;
            if (lane < 16 && col < OUT_CH) obase[col] = mx;
        }
    }
}

// ---------- fused: conv (blocks < CONV_BLOCKS) + word-emb copy (rest) ----------
__global__ void __launch_bounds__(256)
fused_kernel(const int* __restrict__ words, const int* __restrict__ chars,
             const float* __restrict__ W_word, const ushort* __restrict__ ws,
             const float* __restrict__ conv_b, float* __restrict__ out) {
    const int wave = threadIdx.x >> 6;
    const int lane = threadIdx.x & 63;

    if (blockIdx.x >= CONV_BLOCKS) {
        // word embedding: one wave per output row, float4 copy
        const int m   = (blockIdx.x - CONV_BLOCKS) * 4 + wave;
        const int idx = words[m];
        const float4v* __restrict__ src = (const float4v*)(W_word + (size_t)idx * D_WORDE);
        float4v* __restrict__ dst = (float4v*)(out + (size_t)m * D_OUT);
        #pragma unroll
        for (int j = lane; j < D_WORDE / 4; j += 64) dst[j] = src[j];
        return;
    }

    const ushort* __restrict__ charP = ws;
    const ushort* __restrict__ WO    = ws + CHARP_U16;
    const int u = blockIdx.x * 4 + wave;

    if (u < 4 * CLASS_WAVES) {
        const int cls   = u >> 11;
        const int chunk = u & (CLASS_WAVES - 1);
        conv_wave<3, 8>(cls * 3, chunk * 8, lane, chars, charP, WO, conv_b, out);
    } else {
        const int chunk = u - 4 * CLASS_WAVES;
        conv_wave<1, 32>(12, chunk * 32, lane, chars, charP, WO, conv_b, out);
    }
}

// ---------- fallbacks (tiny ws): round-1 proven kernels ----------
__global__ void __launch_bounds__(256)
word_emb_kernel(const int* __restrict__ words, const float* __restrict__ W_word,
                float* __restrict__ out) {
    int wave = threadIdx.x >> 6, lane = threadIdx.x & 63;
    int m = blockIdx.x * 4 + wave;
    int idx = words[m];
    const float* __restrict__ src = W_word + (size_t)idx * D_WORDE;
    float* __restrict__ dst = out + (size_t)m * D_OUT;
    for (int j = lane; j < D_WORDE; j += 64) dst[j] = src[j];
}

__global__ void __launch_bounds__(256)
char_conv_f32_kernel(const int* __restrict__ chars, const float* __restrict__ W_char,
                     const float* __restrict__ conv_w, const float* __restrict__ conv_b,
                     float* __restrict__ out) {
    __shared__ __align__(16) float xs[D_CHARE * WLEN];
    __shared__ int ids[WLEN];
    int m = blockIdx.x, s = m >> 6, b = m & 63, tid = threadIdx.x;
    if (tid < WLEN) ids[tid] = chars[(b * SENT + s) * WLEN + tid];
    __syncthreads();
    for (int e = tid; e < D_CHARE * WLEN; e += 256) {
        int c = e >> 4, l = e & 15;
        xs[e] = W_char[ids[l] * D_CHARE + c];
    }
    __syncthreads();
    if (tid < OUT_CH) {
        float acc[NPOS];
        #pragma unroll
        for (int p = 0; p < NPOS; p++) acc[p] = 0.f;
        const float4* xs4 = (const float4*)xs;
        for (int c = 0; c < D_CHARE; c++) {
            float4 a0 = xs4[c*4+0], a1 = xs4[c*4+1], a2 = xs4[c*4+2], a3 = xs4[c*4+3];
            float xr[WLEN] = {a0.x,a0.y,a0.z,a0.w, a1.x,a1.y,a1.z,a1.w,
                              a2.x,a2.y,a2.z,a2.w, a3.x,a3.y,a3.z,a3.w};
            #pragma unroll
            for (int k = 0; k < KSIZE; k++) {
                float wv = conv_w[tid * (D_CHARE * KSIZE) + c * KSIZE + k];
                #pragma unroll
                for (int p = 0; p < NPOS; p++) acc[p] = fmaf(wv, xr[p + k], acc[p]);
            }
        }
        float mx = acc[0];
        #pragma unroll
        for (int p = 1; p < NPOS; p++) mx = fmaxf(mx, acc[p]);
        out[(size_t)m * D_OUT + D_WORDE + tid] = mx + conv_b[tid];
    }
}

extern "C" void kernel_launch(void* const* d_in, const int* in_sizes, int n_in,
                              void* d_out, int out_size, void* d_ws, size_t ws_size,
                              hipStream_t stream) {
    const int*   words  = (const int*)d_in[0];
    const int*   chars  = (const int*)d_in[1];
    const float* W_word = (const float*)d_in[2];
    const float* W_char = (const float*)d_in[3];
    const float* conv_w = (const float*)d_in[4];
    const float* conv_b = (const float*)d_in[5];
    float* out = (float*)d_out;

    if (ws_size >= WS_NEED) {
        ushort* ws = (ushort*)d_ws;
        hipLaunchKernelGGL(prep_kernel,
                           dim3((CHARP_U16 + WO_U16 + 255) / 256), dim3(256), 0, stream,
                           W_char, conv_w, ws);
        hipLaunchKernelGGL(fused_kernel, dim3(CONV_BLOCKS + EMB_BLOCKS), dim3(256),
                           0, stream, words, chars, W_word, ws, conv_b, out);
    } else {
        hipLaunchKernelGGL(word_emb_kernel, dim3(NWORDS / 4), dim3(256), 0, stream,
                           words, W_word, out);
        hipLaunchKernelGGL(char_conv_f32_kernel, dim3(NWORDS), dim3(256), 0, stream,
                           chars, W_char, conv_w, conv_b, out);
    }
}

// Round 4
// 54.553 us; speedup vs baseline: 1.9017x; 1.9017x over previous
//
#include <hip/hip_runtime.h>

#define SENT    256
#define BATCH   64
#define WLEN    16
#define D_WORDE 300
#define D_CHARE 50
#define OUT_CH  200
#define KSIZE   3
#define NPOS    14
#define D_OUT   500
#define NWORDS  (SENT * BATCH)

// GEMM geometry: M=16 positions/word, N=13x16=208, K=3*64=192 (kg=kk*64+c)
#define KPAD      192
#define MPAD      208
#define CHARP_U16 (129 * 64)          // row 128 = zeros (conv rows 16/17)
#define WO_U16    (MPAD * KPAD)
#define WS_NEED   ((size_t)(CHARP_U16 + WO_U16) * 2)

#define WPB         8                 // words per conv block
#define TILE_U16    1160              // 18*64 + 8 pad (per-word LDS tile, ushorts)
#define CONV_BLOCKS (NWORDS / WPB)    // 2048
#define EMB_BLOCKS  (NWORDS / 4)      // 4096
#define GRID        (CONV_BLOCKS + EMB_BLOCKS)   // 6144

typedef short  short8  __attribute__((ext_vector_type(8)));
typedef ushort ushort8 __attribute__((ext_vector_type(8)));
typedef float  float4v __attribute__((ext_vector_type(4)));

__device__ __forceinline__ ushort f2bf(float f) {
    unsigned u = __float_as_uint(f);
    u = (u + 0x7FFFu + ((u >> 16) & 1u)) >> 16;   // RNE
    return (ushort)u;
}

// ---------- prep: bf16 char table (129 rows) + K-major conv weights ----------
__global__ void prep_kernel(const float* __restrict__ W_char,
                            const float* __restrict__ conv_w,
                            ushort* __restrict__ ws) {
    int j = blockIdx.x * 256 + threadIdx.x;
    if (j < CHARP_U16) {
        int r = j >> 6, c = j & 63;
        ws[j] = (r < 128 && c < D_CHARE) ? f2bf(W_char[r * D_CHARE + c]) : (ushort)0;
    }
    int j2 = j - CHARP_U16;
    if (j2 >= 0 && j2 < WO_U16) {
        int o = j2 / KPAD, kg = j2 - o * KPAD;
        int kk = kg >> 6, c = kg & 63;
        float v = (o < OUT_CH && c < D_CHARE)
                    ? conv_w[o * (D_CHARE * KSIZE) + c * KSIZE + kk] : 0.f;
        ws[CHARP_U16 + j2] = f2bf(v);
    }
}

__device__ __forceinline__ float redmax14(float4v d, int lg) {
    float m01 = fmaxf(d[0], d[1]);
    float m23 = fmaxf(d[2], d[3]);
    float m = (lg == 3) ? m01 : fmaxf(m01, m23);   // rows 14,15 invalid
    m = fmaxf(m, __shfl_xor(m, 16, 64));
    m = fmaxf(m, __shfl_xor(m, 32, 64));
    return m;
}

// ---------- fused: conv (blockIdx%3==0) + word-emb copy (others) ----------
__global__ void __launch_bounds__(256, 4)
fused_kernel(const int* __restrict__ words, const int* __restrict__ chars,
             const float* __restrict__ W_word, const ushort* __restrict__ ws,
             const float* __restrict__ conv_b, float* __restrict__ out) {
    __shared__ __align__(16) ushort smem[WPB * TILE_U16];
    __shared__ int ids[WPB * WLEN];

    const int tid  = threadIdx.x;
    const int lane = tid & 63;
    const int wave = tid >> 6;

    if (blockIdx.x % 3 != 0) {
        // ---- word embedding: one wave per output row, float4 copy
        const int eb = blockIdx.x - blockIdx.x / 3 - 1;       // 0..4095
        const int m  = eb * 4 + wave;
        const int idx = words[m];
        const float4v* __restrict__ src = (const float4v*)(W_word + (size_t)idx * D_WORDE);
        float4v* __restrict__ dst = (float4v*)(out + (size_t)m * D_OUT);
        dst[lane] = src[lane];                                 // 75 float4 per row
        if (lane < 75 - 64) dst[64 + lane] = src[64 + lane];
        return;
    }

    const ushort* __restrict__ charP = ws;
    const ushort* __restrict__ WO    = ws + CHARP_U16;
    const int block0 = (blockIdx.x / 3) * WPB;
    const int l15 = lane & 15;
    const int lg  = lane >> 4;

    // ---- stage char ids
    if (tid < WPB * WLEN) {
        int w = tid >> 4, l = tid & 15;
        int m = block0 + w;
        ids[tid] = chars[((m & 63) * SENT + (m >> 6)) * WLEN + l];
    }
    __syncthreads();

    // ---- stage 8 word-tiles (18 rows x 64 bf16, XOR-swizzled 16B blocks)
    #pragma unroll
    for (int task = tid; task < WPB * 144; task += 256) {
        int word = task / 144;
        int rem  = task - word * 144;
        int l = rem >> 3, blk = rem & 7;
        ushort8 v = {};
        if (l < WLEN) {
            int id = ids[(word << 4) | l];
            v = *(const ushort8*)&charP[id * 64 + blk * 8];
        }
        *(ushort8*)&smem[word * TILE_U16 + l * 64 + ((blk ^ (l & 7)) << 3)] = v;
    }
    __syncthreads();

    // ---- phase 1: wave w owns N-tiles {w, w+4, w+8}; all 8 words
    short8 B[3][6];
    float  bv[3];
    #pragma unroll
    for (int i = 0; i < 3; i++) {
        int col = (wave + 4 * i) * 16 + l15;                  // <= 191, all valid
        #pragma unroll
        for (int s = 0; s < 6; s++)
            B[i][s] = *(const short8*)&WO[col * KPAD + s * 32 + lg * 8];
        bv[i] = conv_b[col];
    }

    #pragma unroll 1
    for (int r = 0; r < WPB; r++) {
        const int base = r * TILE_U16;
        short8 a[6];
        #pragma unroll
        for (int s = 0; s < 6; s++) {
            int l  = l15 + (s >> 1);
            int bb = (((s & 1) * 4 + lg) ^ (l & 7));
            a[s] = *(const short8*)&smem[base + l * 64 + (bb << 3)];
        }
        float4v acc[3];
        #pragma unroll
        for (int i = 0; i < 3; i++) acc[i] = (float4v){0, 0, 0, 0};
        #pragma unroll
        for (int s = 0; s < 6; s++)
            #pragma unroll
            for (int i = 0; i < 3; i++)
                acc[i] = __builtin_amdgcn_mfma_f32_16x16x32_bf16(a[s], B[i][s], acc[i], 0, 0, 0);

        float* obase = out + (size_t)(block0 + r) * D_OUT + D_WORDE;
        #pragma unroll
        for (int i = 0; i < 3; i++) {
            float mx = redmax14(acc[i], lg) + bv[i];
            if (lane < 16) obase[(wave + 4 * i) * 16 + lane] = mx;
        }
    }

    // ---- phase 2: tile 12 (channels 192..199); wave w does words {2w, 2w+1}
    short8 B12[6];
    #pragma unroll
    for (int s = 0; s < 6; s++)
        B12[s] = *(const short8*)&WO[(192 + l15) * KPAD + s * 32 + lg * 8];
    const float bv12 = (192 + l15 < OUT_CH) ? conv_b[192 + l15] : 0.f;

    #pragma unroll 1
    for (int r2 = 0; r2 < 2; r2++) {
        const int widx = 2 * wave + r2;
        const int base = widx * TILE_U16;
        short8 a[6];
        #pragma unroll
        for (int s = 0; s < 6; s++) {
            int l  = l15 + (s >> 1);
            int bb = (((s & 1) * 4 + lg) ^ (l & 7));
            a[s] = *(const short8*)&smem[base + l * 64 + (bb << 3)];
        }
        float4v acc = {0, 0, 0, 0};
        #pragma unroll
        for (int s = 0; s < 6; s++)
            acc = __builtin_amdgcn_mfma_f32_16x16x32_bf16(a[s], B12[s], acc, 0, 0, 0);
        float mx = redmax14(acc, lg) + bv12;
        if (lane < 8)
            out[(size_t)(block0 + widx) * D_OUT + D_WORDE + 192 + lane] = mx;
    }
}

// ---------- fallbacks (tiny ws): round-1 proven kernels ----------
__global__ void __launch_bounds__(256)
word_emb_kernel(const int* __restrict__ words, const float* __restrict__ W_word,
                float* __restrict__ out) {
    int wave = threadIdx.x >> 6, lane = threadIdx.x & 63;
    int m = blockIdx.x * 4 + wave;
    int idx = words[m];
    const float* __restrict__ src = W_word + (size_t)idx * D_WORDE;
    float* __restrict__ dst = out + (size_t)m * D_OUT;
    for (int j = lane; j < D_WORDE; j += 64) dst[j] = src[j];
}

__global__ void __launch_bounds__(256)
char_conv_f32_kernel(const int* __restrict__ chars, const float* __restrict__ W_char,
                     const float* __restrict__ conv_w, const float* __restrict__ conv_b,
                     float* __restrict__ out) {
    __shared__ __align__(16) float xs[D_CHARE * WLEN];
    __shared__ int ids[WLEN];
    int m = blockIdx.x, s = m >> 6, b = m & 63, tid = threadIdx.x;
    if (tid < WLEN) ids[tid] = chars[(b * SENT + s) * WLEN + tid];
    __syncthreads();
    for (int e = tid; e < D_CHARE * WLEN; e += 256) {
        int c = e >> 4, l = e & 15;
        xs[e] = W_char[ids[l] * D_CHARE + c];
    }
    __syncthreads();
    if (tid < OUT_CH) {
        float acc[NPOS];
        #pragma unroll
        for (int p = 0; p < NPOS; p++) acc[p] = 0.f;
        const float4* xs4 = (const float4*)xs;
        for (int c = 0; c < D_CHARE; c++) {
            float4 a0 = xs4[c*4+0], a1 = xs4[c*4+1], a2 = xs4[c*4+2], a3 = xs4[c*4+3];
            float xr[WLEN] = {a0.x,a0.y,a0.z,a0.w, a1.x,a1.y,a1.z,a1.w,
                              a2.x,a2.y,a2.z,a2.w, a3.x,a3.y,a3.z,a3.w};
            #pragma unroll
            for (int k = 0; k < KSIZE; k++) {
                float wv = conv_w[tid * (D_CHARE * KSIZE) + c * KSIZE + k];
                #pragma unroll
                for (int p = 0; p < NPOS; p++) acc[p] = fmaf(wv, xr[p + k], acc[p]);
            }
        }
        float mx = acc[0];
        #pragma unroll
        for (int p = 1; p < NPOS; p++) mx = fmaxf(mx, acc[p]);
        out[(size_t)m * D_OUT + D_WORDE + tid] = mx + conv_b[tid];
    }
}

extern "C" void kernel_launch(void* const* d_in, const int* in_sizes, int n_in,
                              void* d_out, int out_size, void* d_ws, size_t ws_size,
                              hipStream_t stream) {
    const int*   words  = (const int*)d_in[0];
    const int*   chars  = (const int*)d_in[1];
    const float* W_word = (const float*)d_in[2];
    const float* W_char = (const float*)d_in[3];
    const float* conv_w = (const float*)d_in[4];
    const float* conv_b = (const float*)d_in[5];
    float* out = (float*)d_out;

    if (ws_size >= WS_NEED) {
        ushort* ws = (ushort*)d_ws;
        hipLaunchKernelGGL(prep_kernel,
                           dim3((CHARP_U16 + WO_U16 + 255) / 256), dim3(256), 0, stream,
                           W_char, conv_w, ws);
        hipLaunchKernelGGL(fused_kernel, dim3(GRID), dim3(256), 0, stream,
                           words, chars, W_word, ws, conv_b, out);
    } else {
        hipLaunchKernelGGL(word_emb_kernel, dim3(NWORDS / 4), dim3(256), 0, stream,
                           words, W_word, out);
        hipLaunchKernelGGL(char_conv_f32_kernel, dim3(NWORDS), dim3(256), 0, stream,
                           chars, W_char, conv_w, conv_b, out);
    }
}